// Round 5
// baseline (46.913 us; speedup 1.0000x reference)
//
#include <hip/hip_runtime.h>
#include <hip/hip_fp16.h>
#include <math.h>

// f(x) = tanh-MLP(x), 1->16->32->32->16->3, per scalar element.
// Table entries are 16B: three fp16 PAIRS (both lerp endpoints, 3 channels)
// -> ONE random gather per element (4.19M total) instead of 4 per out-float4
// (12.6M) as in R1-R4. Gather serialization was the shared bottleneck theory.

#define TN 2048
#define XLO (-10.0f)
#define XHI (10.0f)

__device__ __forceinline__ float fast_tanh(float x) {
    float t = __builtin_amdgcn_exp2f(x * 2.885390081777927f);
    return 1.0f - 2.0f * __builtin_amdgcn_rcpf(t + 1.0f);
}

// Weights staged to LDS transposed (output-neuron-major), rows 16B-aligned.
// Block: 128 threads. Wave0 lanes compute points base+0..63; wave1 lane 64
// computes point base+64 (needed for the pair of entry base+63). LDS exchange,
// then lanes 0..63 pack and store fp16-pair entries.
__global__ __launch_bounds__(128) void build_table(
    const float* __restrict__ W0, const float* __restrict__ b0,
    const float* __restrict__ W1, const float* __restrict__ b1,
    const float* __restrict__ W2, const float* __restrict__ b2,
    const float* __restrict__ W3, const float* __restrict__ b3,
    const float* __restrict__ W4, const float* __restrict__ b4,
    uint4* __restrict__ table)
{
    __shared__ __align__(16) float w[2224];
    __shared__ float4 o_lds[65];
    const int t = threadIdx.x;

    for (int i = t; i < 16;  i += 128) { w[i] = W0[i]; w[16 + i] = b0[i]; }
    for (int i = t; i < 512; i += 128) { int k = i >> 5, j = i & 31; w[32   + j * 16 + k] = W1[i]; }
    for (int i = t; i < 32;  i += 128) w[544  + i] = b1[i];
    for (int i = t; i < 1024;i += 128) { int k = i >> 5, j = i & 31; w[576  + j * 32 + k] = W2[i]; }
    for (int i = t; i < 32;  i += 128) w[1600 + i] = b2[i];
    for (int i = t; i < 512; i += 128) { int k = i >> 4, j = i & 15; w[1632 + j * 32 + k] = W3[i]; }
    for (int i = t; i < 16;  i += 128) w[2144 + i] = b3[i];
    for (int i = t; i < 48;  i += 128) { int k = i / 3, j = i - 3 * k; w[2160 + j * 16 + k] = W4[i]; }
    if (t < 3) w[2208 + t] = b4[t];
    __syncthreads();

    const int base = blockIdx.x * 64;
    if (t <= 64) {
        int cp = min(base + ((t < 64) ? t : 64), TN - 1);
        const float h = (XHI - XLO) / (float)(TN - 1);
        const float x = XLO + (float)cp * h;
        const float4* L4 = (const float4*)w;

        float a[32], c[32];
        #pragma unroll
        for (int q = 0; q < 4; ++q) {
            float4 wq = L4[q];
            float4 bq = L4[4 + q];
            a[4 * q + 0] = fast_tanh(fmaf(x, wq.x, bq.x));
            a[4 * q + 1] = fast_tanh(fmaf(x, wq.y, bq.y));
            a[4 * q + 2] = fast_tanh(fmaf(x, wq.z, bq.z));
            a[4 * q + 3] = fast_tanh(fmaf(x, wq.w, bq.w));
        }
        #pragma unroll
        for (int j = 0; j < 32; ++j) {
            float acc = w[544 + j];
            #pragma unroll
            for (int q = 0; q < 4; ++q) {
                float4 wq = L4[8 + j * 4 + q];
                acc = fmaf(a[4 * q + 0], wq.x, acc);
                acc = fmaf(a[4 * q + 1], wq.y, acc);
                acc = fmaf(a[4 * q + 2], wq.z, acc);
                acc = fmaf(a[4 * q + 3], wq.w, acc);
            }
            c[j] = fast_tanh(acc);
        }
        #pragma unroll
        for (int j = 0; j < 32; ++j) {
            float acc = w[1600 + j];
            #pragma unroll
            for (int q = 0; q < 8; ++q) {
                float4 wq = L4[144 + j * 8 + q];
                acc = fmaf(c[4 * q + 0], wq.x, acc);
                acc = fmaf(c[4 * q + 1], wq.y, acc);
                acc = fmaf(c[4 * q + 2], wq.z, acc);
                acc = fmaf(c[4 * q + 3], wq.w, acc);
            }
            a[j] = fast_tanh(acc);
        }
        #pragma unroll
        for (int j = 0; j < 16; ++j) {
            float acc = w[2144 + j];
            #pragma unroll
            for (int q = 0; q < 8; ++q) {
                float4 wq = L4[408 + j * 8 + q];
                acc = fmaf(a[4 * q + 0], wq.x, acc);
                acc = fmaf(a[4 * q + 1], wq.y, acc);
                acc = fmaf(a[4 * q + 2], wq.z, acc);
                acc = fmaf(a[4 * q + 3], wq.w, acc);
            }
            c[j] = fast_tanh(acc);
        }
        float o[3];
        #pragma unroll
        for (int j = 0; j < 3; ++j) {
            float acc = w[2208 + j];
            #pragma unroll
            for (int q = 0; q < 4; ++q) {
                float4 wq = L4[540 + j * 4 + q];
                acc = fmaf(c[4 * q + 0], wq.x, acc);
                acc = fmaf(c[4 * q + 1], wq.y, acc);
                acc = fmaf(c[4 * q + 2], wq.z, acc);
                acc = fmaf(c[4 * q + 3], wq.w, acc);
            }
            o[j] = fast_tanh(acc);
        }
        o_lds[t] = make_float4(o[0], o[1], o[2], 0.0f);
    }
    __syncthreads();

    if (t < 64) {
        float4 lo = o_lds[t];
        float4 hi = o_lds[t + 1];
        __half2 p0 = __floats2half2_rn(lo.x, hi.x);   // .x = f(i), .y = f(i+1)
        __half2 p1 = __floats2half2_rn(lo.y, hi.y);
        __half2 p2 = __floats2half2_rn(lo.z, hi.z);
        uint4 e;
        e.x = *reinterpret_cast<unsigned*>(&p0);
        e.y = *reinterpret_cast<unsigned*>(&p1);
        e.z = *reinterpret_cast<unsigned*>(&p2);
        e.w = 0u;
        table[base + t] = e;
    }
}

__device__ __forceinline__ void lerp_entry(const uint4* __restrict__ tab,
                                           float inv_h, float x,
                                           float& y0, float& y1, float& y2)
{
    float xc = fminf(fmaxf(x, XLO), XHI);
    float f  = (xc - XLO) * inv_h;
    int i0 = (int)f;
    i0 = min(i0, TN - 2);
    float fr = f - (float)i0;
    uint4 e = tab[i0];                       // ONE 16B gather: all 6 endpoints
    __half2 h0 = *reinterpret_cast<__half2*>(&e.x);
    __half2 h1 = *reinterpret_cast<__half2*>(&e.y);
    __half2 h2 = *reinterpret_cast<__half2*>(&e.z);
    float2 p0 = __half22float2(h0);
    float2 p1 = __half22float2(h1);
    float2 p2 = __half22float2(h2);
    y0 = fmaf(fr, p0.y - p0.x, p0.x);
    y1 = fmaf(fr, p1.y - p1.x, p1.x);
    y2 = fmaf(fr, p2.y - p2.x, p2.x);
}

__global__ __launch_bounds__(256) void apply_pairs(
    const float4* __restrict__ x4, const uint4* __restrict__ tab_g,
    float4* __restrict__ out4, unsigned n_units)
{
    __shared__ uint4 tab[TN];   // 32 KB -> 5 blocks/CU
    for (int i = threadIdx.x; i < TN; i += 256) tab[i] = tab_g[i];
    __syncthreads();

    const float inv_h = (float)(TN - 1) / (XHI - XLO);
    unsigned stride = gridDim.x * 256u;
    for (unsigned u = blockIdx.x * 256u + threadIdx.x; u < n_units; u += stride) {
        float4 xv = x4[u];                   // 4 elements, coalesced
        float a0, a1, a2, e0, e1, e2, c0, c1, c2, d0, d1, d2;
        lerp_entry(tab, inv_h, xv.x, a0, a1, a2);
        lerp_entry(tab, inv_h, xv.y, e0, e1, e2);
        lerp_entry(tab, inv_h, xv.z, c0, c1, c2);
        lerp_entry(tab, inv_h, xv.w, d0, d1, d2);
        float4* o = out4 + 3u * u;
        o[0] = make_float4(a0, a1, a2, e0);
        o[1] = make_float4(e1, e2, c0, c1);
        o[2] = make_float4(c2, d0, d1, d2);
    }
}

extern "C" void kernel_launch(void* const* d_in, const int* in_sizes, int n_in,
                              void* d_out, int out_size, void* d_ws, size_t ws_size,
                              hipStream_t stream) {
    const float* x  = (const float*)d_in[0];
    const float* W0 = (const float*)d_in[1];
    const float* b0 = (const float*)d_in[2];
    const float* W1 = (const float*)d_in[3];
    const float* b1 = (const float*)d_in[4];
    const float* W2 = (const float*)d_in[5];
    const float* b2 = (const float*)d_in[6];
    const float* W3 = (const float*)d_in[7];
    const float* b3 = (const float*)d_in[8];
    const float* W4 = (const float*)d_in[9];
    const float* b4 = (const float*)d_in[10];
    uint4* table = (uint4*)d_ws;   // TN*16 = 32 KB scratch

    build_table<<<TN / 64, 128, 0, stream>>>(
        W0, b0, W1, b1, W2, b2, W3, b3, W4, b4, table);

    unsigned n_units = (unsigned)in_sizes[0] / 4u;   // 1048576 float4 x-chunks
    int blocks = 1024;
    apply_pairs<<<blocks, 256, 0, stream>>>(
        (const float4*)x, table, (float4*)d_out, n_units);
}

// Round 6
// 43.929 us; speedup vs baseline: 1.0679x; 1.0679x over previous
//
#include <hip/hip_runtime.h>
#include <hip/hip_fp16.h>
#include <math.h>

// f(x) = tanh-MLP(x), 1->16->32->32->16->3, per scalar element.
// R6: table split into THREE 2048-dword channel arrays (each dword = fp16
// pair of lerp endpoints). Random LDS gathers become ds_read_b32 (2-way bank
// aliasing = free, ~6cy) instead of ds_read_b128 (~8-way, ~35cy). Coalesced
// 16B stores (out-float4-major). 24KB LDS -> 6 blocks/CU.

#define TN 2048
#define XLO (-10.0f)
#define XHI (10.0f)

__device__ __forceinline__ float fast_tanh(float x) {
    float t = __builtin_amdgcn_exp2f(x * 2.885390081777927f);
    return 1.0f - 2.0f * __builtin_amdgcn_rcpf(t + 1.0f);
}

// Build: weights LDS-staged transposed; 128-thread blocks, lanes 0..64
// compute 65 consecutive table points, exchange via LDS, lanes 0..63 emit
// fp16-pair dwords into 3 channel arrays at d_ws + {0, TN, 2*TN} dwords.
__global__ __launch_bounds__(128) void build_table(
    const float* __restrict__ W0, const float* __restrict__ b0,
    const float* __restrict__ W1, const float* __restrict__ b1,
    const float* __restrict__ W2, const float* __restrict__ b2,
    const float* __restrict__ W3, const float* __restrict__ b3,
    const float* __restrict__ W4, const float* __restrict__ b4,
    unsigned* __restrict__ tab_g)
{
    __shared__ __align__(16) float w[2224];
    __shared__ float4 o_lds[65];
    const int t = threadIdx.x;

    for (int i = t; i < 16;  i += 128) { w[i] = W0[i]; w[16 + i] = b0[i]; }
    for (int i = t; i < 512; i += 128) { int k = i >> 5, j = i & 31; w[32   + j * 16 + k] = W1[i]; }
    for (int i = t; i < 32;  i += 128) w[544  + i] = b1[i];
    for (int i = t; i < 1024;i += 128) { int k = i >> 5, j = i & 31; w[576  + j * 32 + k] = W2[i]; }
    for (int i = t; i < 32;  i += 128) w[1600 + i] = b2[i];
    for (int i = t; i < 512; i += 128) { int k = i >> 4, j = i & 15; w[1632 + j * 32 + k] = W3[i]; }
    for (int i = t; i < 16;  i += 128) w[2144 + i] = b3[i];
    for (int i = t; i < 48;  i += 128) { int k = i / 3, j = i - 3 * k; w[2160 + j * 16 + k] = W4[i]; }
    if (t < 3) w[2208 + t] = b4[t];
    __syncthreads();

    const int base = blockIdx.x * 64;
    if (t <= 64) {
        int cp = min(base + t, TN - 1);
        const float h = (XHI - XLO) / (float)(TN - 1);
        const float x = XLO + (float)cp * h;
        const float4* L4 = (const float4*)w;

        float a[32], c[32];
        #pragma unroll
        for (int q = 0; q < 4; ++q) {
            float4 wq = L4[q];
            float4 bq = L4[4 + q];
            a[4 * q + 0] = fast_tanh(fmaf(x, wq.x, bq.x));
            a[4 * q + 1] = fast_tanh(fmaf(x, wq.y, bq.y));
            a[4 * q + 2] = fast_tanh(fmaf(x, wq.z, bq.z));
            a[4 * q + 3] = fast_tanh(fmaf(x, wq.w, bq.w));
        }
        #pragma unroll
        for (int j = 0; j < 32; ++j) {
            float acc = w[544 + j];
            #pragma unroll
            for (int q = 0; q < 4; ++q) {
                float4 wq = L4[8 + j * 4 + q];
                acc = fmaf(a[4 * q + 0], wq.x, acc);
                acc = fmaf(a[4 * q + 1], wq.y, acc);
                acc = fmaf(a[4 * q + 2], wq.z, acc);
                acc = fmaf(a[4 * q + 3], wq.w, acc);
            }
            c[j] = fast_tanh(acc);
        }
        #pragma unroll
        for (int j = 0; j < 32; ++j) {
            float acc = w[1600 + j];
            #pragma unroll
            for (int q = 0; q < 8; ++q) {
                float4 wq = L4[144 + j * 8 + q];
                acc = fmaf(c[4 * q + 0], wq.x, acc);
                acc = fmaf(c[4 * q + 1], wq.y, acc);
                acc = fmaf(c[4 * q + 2], wq.z, acc);
                acc = fmaf(c[4 * q + 3], wq.w, acc);
            }
            a[j] = fast_tanh(acc);
        }
        #pragma unroll
        for (int j = 0; j < 16; ++j) {
            float acc = w[2144 + j];
            #pragma unroll
            for (int q = 0; q < 8; ++q) {
                float4 wq = L4[408 + j * 8 + q];
                acc = fmaf(a[4 * q + 0], wq.x, acc);
                acc = fmaf(a[4 * q + 1], wq.y, acc);
                acc = fmaf(a[4 * q + 2], wq.z, acc);
                acc = fmaf(a[4 * q + 3], wq.w, acc);
            }
            c[j] = fast_tanh(acc);
        }
        float o[3];
        #pragma unroll
        for (int j = 0; j < 3; ++j) {
            float acc = w[2208 + j];
            #pragma unroll
            for (int q = 0; q < 4; ++q) {
                float4 wq = L4[540 + j * 4 + q];
                acc = fmaf(c[4 * q + 0], wq.x, acc);
                acc = fmaf(c[4 * q + 1], wq.y, acc);
                acc = fmaf(c[4 * q + 2], wq.z, acc);
                acc = fmaf(c[4 * q + 3], wq.w, acc);
            }
            o[j] = fast_tanh(acc);
        }
        o_lds[t] = make_float4(o[0], o[1], o[2], 0.0f);
    }
    __syncthreads();

    if (t < 64) {
        float4 lo = o_lds[t];
        float4 hi = o_lds[t + 1];
        __half2 p0 = __floats2half2_rn(lo.x, hi.x);   // .x=f(i), .y=f(i+1)
        __half2 p1 = __floats2half2_rn(lo.y, hi.y);
        __half2 p2 = __floats2half2_rn(lo.z, hi.z);
        tab_g[         base + t] = *reinterpret_cast<unsigned*>(&p0);
        tab_g[TN     + base + t] = *reinterpret_cast<unsigned*>(&p1);
        tab_g[2 * TN + base + t] = *reinterpret_cast<unsigned*>(&p2);
    }
}

__device__ __forceinline__ void lerp3s(
    const unsigned* __restrict__ t0, const unsigned* __restrict__ t1,
    const unsigned* __restrict__ t2, float inv_h, float x,
    float& y0, float& y1, float& y2)
{
    float xc = fminf(fmaxf(x, XLO), XHI);
    float f  = (xc - XLO) * inv_h;
    int i0 = (int)f;
    i0 = min(i0, TN - 2);
    float fr = f - (float)i0;
    unsigned e0 = t0[i0];                 // three independent b32 gathers,
    unsigned e1 = t1[i0];                 // random over 32 banks ~= 2-way
    unsigned e2 = t2[i0];                 // aliasing = conflict-free
    float2 p0 = __half22float2(*reinterpret_cast<__half2*>(&e0));
    float2 p1 = __half22float2(*reinterpret_cast<__half2*>(&e1));
    float2 p2 = __half22float2(*reinterpret_cast<__half2*>(&e2));
    y0 = fmaf(fr, p0.y - p0.x, p0.x);
    y1 = fmaf(fr, p1.y - p1.x, p1.x);
    y2 = fmaf(fr, p2.y - p2.x, p2.x);
}

__global__ __launch_bounds__(256) void apply_s(
    const float* __restrict__ x, const unsigned* __restrict__ tab_g,
    float4* __restrict__ out4, unsigned n_out4)
{
    __shared__ unsigned t0[TN];
    __shared__ unsigned t1[TN];
    __shared__ unsigned t2[TN];
    for (int i = threadIdx.x; i < TN; i += 256) {
        t0[i] = tab_g[i];
        t1[i] = tab_g[TN + i];
        t2[i] = tab_g[2 * TN + i];
    }
    __syncthreads();

    const float inv_h = (float)(TN - 1) / (XHI - XLO);
    unsigned stride = gridDim.x * 256u;
    for (unsigned g = blockIdx.x * 256u + threadIdx.x; g < n_out4; g += stride) {
        unsigned e = (4u * g) / 3u;          // first input element needed
        unsigned r = 4u * g - 3u * e;        // 0,1,2
        float x0 = x[e];
        float x1 = x[e + 1];
        float s0, s1, s2, s3, s4, s5;
        lerp3s(t0, t1, t2, inv_h, x0, s0, s1, s2);
        lerp3s(t0, t1, t2, inv_h, x1, s3, s4, s5);
        float4 o;
        o.x = (r == 0u) ? s0 : ((r == 1u) ? s1 : s2);
        o.y = (r == 0u) ? s1 : ((r == 1u) ? s2 : s3);
        o.z = (r == 0u) ? s2 : ((r == 1u) ? s3 : s4);
        o.w = (r == 0u) ? s3 : ((r == 1u) ? s4 : s5);
        out4[g] = o;                         // one coalesced 16B store
    }
}

extern "C" void kernel_launch(void* const* d_in, const int* in_sizes, int n_in,
                              void* d_out, int out_size, void* d_ws, size_t ws_size,
                              hipStream_t stream) {
    const float* x  = (const float*)d_in[0];
    const float* W0 = (const float*)d_in[1];
    const float* b0 = (const float*)d_in[2];
    const float* W1 = (const float*)d_in[3];
    const float* b1 = (const float*)d_in[4];
    const float* W2 = (const float*)d_in[5];
    const float* b2 = (const float*)d_in[6];
    const float* W3 = (const float*)d_in[7];
    const float* b3 = (const float*)d_in[8];
    const float* W4 = (const float*)d_in[9];
    const float* b4 = (const float*)d_in[10];
    unsigned* tab = (unsigned*)d_ws;   // 3*TN*4 = 24 KB scratch

    build_table<<<TN / 64, 128, 0, stream>>>(
        W0, b0, W1, b1, W2, b2, W3, b3, W4, b4, tab);

    unsigned n_out4 = (unsigned)out_size / 4u;   // 3145728
    int blocks = 1536;                           // 6 blocks/CU (24KB LDS)
    apply_s<<<blocks, 256, 0, stream>>>(
        x, tab, (float4*)d_out, n_out4);
}